// Round 1
// baseline (441.075 us; speedup 1.0000x reference)
//
#include <hip/hip_runtime.h>

#define DIM 32
#define NPB 128            // nodes per bucket
#define NPB_SHIFT 7
#define NPB_MASK 127
#define MAXB 1024          // max buckets supported
#define PCHUNK 2048        // edges per partition block (512 thr x 4)
#define CAPB 4096          // per-bucket packed capacity (>= 2x mean, gated host-side)
#define TILE 8192          // legacy scan tile (fallback path)

__global__ void zero_i32_kernel(int* __restrict__ p, int n) {
    int t = blockIdx.x * blockDim.x + threadIdx.x;
    if (t < n) p[t] = 0;
}

// ============ fast path: fixed-capacity bucket partition + LDS-atomic accum ===

// Partition edges into fixed-capacity bucket regions packed[b*CAPB ...].
// Per block: LDS count (atomic return = local rank), one global atomicAdd per
// touched bucket to reserve a contiguous slice, then scatter.
// packed = (src << NPB_SHIFT) | (dst & NPB_MASK). Order within bucket is
// nondeterministic (FP sum reorder noise only).
__global__ void __launch_bounds__(512)
partition_cap_kernel(const int* __restrict__ src, const int* __restrict__ dst,
                     int* __restrict__ gcur, int* __restrict__ packed,
                     int n_edges, int nbuckets) {
    __shared__ int lcnt[MAXB];
    __shared__ int lbase[MAXB];
    int t = threadIdx.x;
    for (int j = t; j < nbuckets; j += 512) lcnt[j] = 0;
    __syncthreads();

    int e0 = blockIdx.x * PCHUNK + t * 4;
    int bb[4], rr[4], pk[4];
    int nv = 0;
    if (e0 + 3 < n_edges) {
        int4 d = *(const int4*)(dst + e0);
        int4 s = *(const int4*)(src + e0);
        bb[0] = d.x >> NPB_SHIFT; pk[0] = (s.x << NPB_SHIFT) | (d.x & NPB_MASK);
        bb[1] = d.y >> NPB_SHIFT; pk[1] = (s.y << NPB_SHIFT) | (d.y & NPB_MASK);
        bb[2] = d.z >> NPB_SHIFT; pk[2] = (s.z << NPB_SHIFT) | (d.z & NPB_MASK);
        bb[3] = d.w >> NPB_SHIFT; pk[3] = (s.w << NPB_SHIFT) | (d.w & NPB_MASK);
        nv = 4;
    } else {
        for (int k = e0; k < n_edges; ++k) {
            int d = dst[k];
            bb[nv] = d >> NPB_SHIFT;
            pk[nv] = (src[k] << NPB_SHIFT) | (d & NPB_MASK);
            ++nv;
        }
    }
#pragma unroll
    for (int k = 0; k < 4; ++k)
        if (k < nv) rr[k] = atomicAdd(&lcnt[bb[k]], 1);
    __syncthreads();
    for (int j = t; j < nbuckets; j += 512) {
        int c = lcnt[j];
        if (c > 0) lbase[j] = j * CAPB + atomicAdd(&gcur[j], c);
    }
    __syncthreads();
#pragma unroll
    for (int k = 0; k < 4; ++k)
        if (k < nv) {
            int b = bb[k];
            int pos = lbase[b] + rr[k];
            if (pos < (b + 1) * CAPB) packed[pos] = pk[k];  // overflow guard
        }
}

// LDS layout swizzle: acc float index = ld*32 + ((f + 4*ld) & 31).
// Within an 8-lane edge-group (fixed ld, f = q*4+c) -> 8 distinct banks;
// across groups the +4*ld term spreads the bank sets -> ~2-way avg (free).
__device__ __forceinline__ int aidx(int ld, int f) {
    return (ld << 5) + ((f + (ld << 2)) & 31);
}

// One 512-thread block per 128-node bucket. Divergence-free edge-parallel
// loop: 8 lanes per edge, each lane loads one float4 of x[src] and does 4
// ds_add_f32 into the swizzled LDS accumulator. Epilogue divides by degree.
__global__ void __launch_bounds__(512)
bucket_accum_kernel(const float4* __restrict__ x4,
                    const int* __restrict__ gcur,
                    const int* __restrict__ packed,
                    float4* __restrict__ out4, int n_nodes) {
    __shared__ float acc[NPB * DIM];   // 16 KB
    __shared__ int scnt[NPB];
    int b = blockIdx.x;
    int t = threadIdx.x;
    for (int j = t; j < NPB * DIM; j += 512) acc[j] = 0.0f;
    if (t < NPB) scnt[t] = 0;
    __syncthreads();

    int ecnt = gcur[b];
    if (ecnt > CAPB) ecnt = CAPB;      // matches partition overflow guard
    const int* seg = packed + (size_t)b * CAPB;

    int g  = t >> 3;                   // edge group 0..63
    int q  = t & 7;                    // feature quad
    int f0 = q << 2;
#pragma unroll 2
    for (int e = g; e < ecnt; e += 64) {
        int p    = seg[e];
        int ld   = p & NPB_MASK;
        int srow = p >> NPB_SHIFT;
        float4 v = x4[srow * 8 + q];
        atomicAdd(&acc[aidx(ld, f0 + 0)], v.x);
        atomicAdd(&acc[aidx(ld, f0 + 1)], v.y);
        atomicAdd(&acc[aidx(ld, f0 + 2)], v.z);
        atomicAdd(&acc[aidx(ld, f0 + 3)], v.w);
        if (q == 0) atomicAdd(&scnt[ld], 1);
    }
    __syncthreads();

    int n0 = b << NPB_SHIFT;
    for (int j = t; j < NPB * 8; j += 512) {
        int node = j >> 3;
        int qq   = j & 7;
        int gn   = n0 + node;
        if (gn < n_nodes) {
            float inv = 1.0f / (float)max(scnt[node], 1);
            int fb = qq << 2;
            float4 r;
            r.x = acc[aidx(node, fb + 0)] * inv;
            r.y = acc[aidx(node, fb + 1)] * inv;
            r.z = acc[aidx(node, fb + 2)] * inv;
            r.w = acc[aidx(node, fb + 3)] * inv;
            out4[(size_t)gn * 8 + qq] = r;
        }
    }
}

// ================= fallback: sorted (pull) path =================

__global__ void hist_kernel(const int* __restrict__ dst, int* __restrict__ counts,
                            int n_edges) {
    int t = blockIdx.x * blockDim.x + threadIdx.x;
    if (t < n_edges) atomicAdd(&counts[dst[t]], 1);
}

__global__ void scan_part1(const int* __restrict__ counts,
                           int* __restrict__ block_sums, int n) {
    __shared__ int sh[256];
    int base = blockIdx.x * TILE + threadIdx.x * 32;
    int s = 0;
#pragma unroll
    for (int i = 0; i < 32; ++i) {
        int idx = base + i;
        if (idx < n) s += counts[idx];
    }
    sh[threadIdx.x] = s;
    __syncthreads();
    for (int off = 128; off > 0; off >>= 1) {
        if (threadIdx.x < off) sh[threadIdx.x] += sh[threadIdx.x + off];
        __syncthreads();
    }
    if (threadIdx.x == 0) block_sums[blockIdx.x] = sh[0];
}

__global__ void scan_part2(int* __restrict__ block_sums, int nb) {
    if (blockIdx.x == 0 && threadIdx.x == 0) {
        int run = 0;
        for (int i = 0; i < nb; ++i) {
            int v = block_sums[i];
            block_sums[i] = run;
            run += v;
        }
    }
}

__global__ void scan_part3(const int* __restrict__ counts,
                           const int* __restrict__ block_sums,
                           int* __restrict__ offsets, int n) {
    __shared__ int sh[256];
    int tid = threadIdx.x;
    int base = blockIdx.x * TILE + tid * 32;
    int local[32];
    int s = 0;
#pragma unroll
    for (int i = 0; i < 32; ++i) {
        int idx = base + i;
        int v = (idx < n) ? counts[idx] : 0;
        local[i] = v;
        s += v;
    }
    sh[tid] = s;
    __syncthreads();
    for (int off = 1; off < 256; off <<= 1) {
        int v = (tid >= off) ? sh[tid - off] : 0;
        __syncthreads();
        sh[tid] += v;
        __syncthreads();
    }
    int run = block_sums[blockIdx.x] + ((tid == 0) ? 0 : sh[tid - 1]);
#pragma unroll
    for (int i = 0; i < 32; ++i) {
        int idx = base + i;
        if (idx < n) offsets[idx] = run;
        run += local[i];
    }
}

__global__ void scatter_sort_kernel(const int* __restrict__ src,
                                    const int* __restrict__ dst,
                                    int* __restrict__ cursors,
                                    int* __restrict__ sorted_src,
                                    int n_edges) {
    int t = blockIdx.x * blockDim.x + threadIdx.x;
    if (t < n_edges) {
        int pos = atomicAdd(&cursors[dst[t]], 1);
        sorted_src[pos] = src[t];
    }
}

__device__ inline void f4add(float4& a, float4 v) {
    a.x += v.x; a.y += v.y; a.z += v.z; a.w += v.w;
}

__global__ void aggregate_kernel(const float* __restrict__ x,
                                 const int* __restrict__ seg_end,
                                 const int* __restrict__ sorted_src,
                                 float4* __restrict__ out,
                                 int n_nodes) {
    int t = blockIdx.x * blockDim.x + threadIdx.x;
    int n = t >> 3;
    if (n >= n_nodes) return;
    int q = t & 7;
    int end   = seg_end[n];
    int start = (n == 0) ? 0 : seg_end[n - 1];
    const float4* x4 = (const float4*)x;
    float4 acc0 = make_float4(0.f, 0.f, 0.f, 0.f);
    float4 acc1 = make_float4(0.f, 0.f, 0.f, 0.f);
    int k = start;
    for (; k + 1 < end; k += 2) {
        int s0 = sorted_src[k];
        int s1 = sorted_src[k + 1];
        f4add(acc0, x4[s0 * 8 + q]);
        f4add(acc1, x4[s1 * 8 + q]);
    }
    if (k < end) f4add(acc0, x4[sorted_src[k] * 8 + q]);
    float inv = 1.0f / (float)max(end - start, 1);
    float4 r;
    r.x = (acc0.x + acc1.x) * inv;
    r.y = (acc0.y + acc1.y) * inv;
    r.z = (acc0.z + acc1.z) * inv;
    r.w = (acc0.w + acc1.w) * inv;
    out[n * 8 + q] = r;
}

// ================= launch =================

extern "C" void kernel_launch(void* const* d_in, const int* in_sizes, int n_in,
                              void* d_out, int out_size, void* d_ws, size_t ws_size,
                              hipStream_t stream) {
    const float* x   = (const float*)d_in[0];
    const int*   src = (const int*)d_in[1];
    const int*   dst = (const int*)d_in[2];
    float* out = (float*)d_out;

    int n_nodes = in_sizes[0] / DIM;
    int n_edges = in_sizes[1];

    int nbuckets = (n_nodes + NPB - 1) >> NPB_SHIFT;
    int pblocks  = (n_edges + PCHUNK - 1) / PCHUNK;
    size_t need = ((size_t)nbuckets * (CAPB + 1)) * sizeof(int);
    bool fast_ok = (n_nodes < (1 << 24)) && (nbuckets <= MAXB) &&
                   ((size_t)n_edges * 2 <= (size_t)nbuckets * CAPB) &&
                   (ws_size >= need);

    if (fast_ok) {
        int* gcur   = (int*)d_ws;            // [nbuckets] cursors (also counts)
        int* packed = gcur + nbuckets;       // [nbuckets * CAPB]

        zero_i32_kernel<<<(nbuckets + 255) / 256, 256, 0, stream>>>(gcur,
                                                                    nbuckets);
        if (pblocks > 0)
            partition_cap_kernel<<<pblocks, 512, 0, stream>>>(src, dst, gcur,
                                                              packed, n_edges,
                                                              nbuckets);
        bucket_accum_kernel<<<nbuckets, 512, 0, stream>>>((const float4*)x,
                                                          gcur, packed,
                                                          (float4*)out,
                                                          n_nodes);
    } else {
        // fallback: dst-sorted pull path (verified generic pipeline)
        int nb = (n_nodes + TILE - 1) / TILE;
        int* counts     = (int*)d_ws;
        int* offsets    = counts + n_nodes;
        int* sorted_src = offsets + n_nodes;
        int* block_sums = sorted_src + n_edges;

        zero_i32_kernel<<<(n_nodes + 255) / 256, 256, 0, stream>>>(counts,
                                                                   n_nodes);
        int eb = (n_edges + 255) / 256;
        hist_kernel<<<eb, 256, 0, stream>>>(dst, counts, n_edges);
        scan_part1<<<nb, 256, 0, stream>>>(counts, block_sums, n_nodes);
        scan_part2<<<1, 64, 0, stream>>>(block_sums, nb);
        scan_part3<<<nb, 256, 0, stream>>>(counts, block_sums, offsets, n_nodes);
        scatter_sort_kernel<<<eb, 256, 0, stream>>>(src, dst, offsets,
                                                    sorted_src, n_edges);
        int athreads = n_nodes * 8;
        int ab = (athreads + 255) / 256;
        aggregate_kernel<<<ab, 256, 0, stream>>>(x, offsets, sorted_src,
                                                 (float4*)out, n_nodes);
    }
}

// Round 2
// 119.791 us; speedup vs baseline: 3.6821x; 3.6821x over previous
//
#include <hip/hip_runtime.h>

#define DIM 32
#define NPB 128            // nodes per bucket
#define NPB_SHIFT 7
#define NPB_MASK 127
#define MAXB 1024          // max buckets supported
#define PCHUNK 8192        // edges per partition block (512 thr x 16)
#define CAPB 4096          // per-bucket packed capacity (>= 2x mean, gated host-side)
#define TILE 8192          // legacy scan tile (fallback path)

__global__ void zero_i32_kernel(int* __restrict__ p, int n) {
    int t = blockIdx.x * blockDim.x + threadIdx.x;
    if (t < n) p[t] = 0;
}

// ====== fast path: fixed-capacity bucket partition + counting-sort accum =====

// Partition edges into fixed-capacity bucket regions packed[b*CAPB ...].
// Per block: stash 16 edges/thread in registers, LDS count (atomic return =
// local rank), ONE global atomicAdd per touched bucket to reserve a contiguous
// slice, then scatter. No fp atomics anywhere in the pipeline.
// packed = (src << NPB_SHIFT) | (dst & NPB_MASK). Order within a bucket is
// nondeterministic (FP sum reorder noise only; aggregation re-sorts anyway).
__global__ void __launch_bounds__(512)
partition_cap_kernel(const int* __restrict__ src, const int* __restrict__ dst,
                     int* __restrict__ gcur, int* __restrict__ packed,
                     int n_edges, int nbuckets) {
    __shared__ int lcnt[MAXB];
    __shared__ int lbase[MAXB];
    int t = threadIdx.x;
    for (int j = t; j < nbuckets; j += 512) lcnt[j] = 0;
    __syncthreads();

    int c0 = blockIdx.x * PCHUNK;
    int c1 = min(c0 + PCHUNK, n_edges);

    int bb[16], pk[16], rr[16];   // static-indexed only (no scratch)
#pragma unroll
    for (int g = 0; g < 4; ++g) {
        int i = c0 + g * 2048 + t * 4;
        int4 d, s;
        if (i + 3 < c1) {
            d = *(const int4*)(dst + i);
            s = *(const int4*)(src + i);
        } else {
            d.x = (i + 0 < c1) ? dst[i + 0] : -1;
            d.y = (i + 1 < c1) ? dst[i + 1] : -1;
            d.z = (i + 2 < c1) ? dst[i + 2] : -1;
            d.w = (i + 3 < c1) ? dst[i + 3] : -1;
            s.x = (i + 0 < c1) ? src[i + 0] : 0;
            s.y = (i + 1 < c1) ? src[i + 1] : 0;
            s.z = (i + 2 < c1) ? src[i + 2] : 0;
            s.w = (i + 3 < c1) ? src[i + 3] : 0;
        }
        bb[g * 4 + 0] = (d.x >= 0) ? (d.x >> NPB_SHIFT) : -1;
        bb[g * 4 + 1] = (d.y >= 0) ? (d.y >> NPB_SHIFT) : -1;
        bb[g * 4 + 2] = (d.z >= 0) ? (d.z >> NPB_SHIFT) : -1;
        bb[g * 4 + 3] = (d.w >= 0) ? (d.w >> NPB_SHIFT) : -1;
        pk[g * 4 + 0] = (s.x << NPB_SHIFT) | (d.x & NPB_MASK);
        pk[g * 4 + 1] = (s.y << NPB_SHIFT) | (d.y & NPB_MASK);
        pk[g * 4 + 2] = (s.z << NPB_SHIFT) | (d.z & NPB_MASK);
        pk[g * 4 + 3] = (s.w << NPB_SHIFT) | (d.w & NPB_MASK);
    }
#pragma unroll
    for (int k = 0; k < 16; ++k)
        if (bb[k] >= 0) rr[k] = atomicAdd(&lcnt[bb[k]], 1);
    __syncthreads();
    for (int j = t; j < nbuckets; j += 512) {
        int c = lcnt[j];
        if (c > 0) lbase[j] = j * CAPB + atomicAdd(&gcur[j], c);
    }
    __syncthreads();
#pragma unroll
    for (int k = 0; k < 16; ++k)
        if (bb[k] >= 0) {
            int b = bb[k];
            int pos = lbase[b] + rr[k];
            if (pos < (b + 1) * CAPB) packed[pos] = pk[k];  // overflow guard
        }
}

__device__ inline void f4add(float4& a, float4 v) {
    a.x += v.x; a.y += v.y; a.z += v.z; a.w += v.w;
}

// Sum x4 rows listed in LDS `sorted[s0 .. s0+cnt)` into two partial float4
// accs — 4 independent gathers in flight per lane.
__device__ inline void accum_node(const float4* __restrict__ x4,
                                  const int* sorted, int s0, int cnt, int q,
                                  float4& accA, float4& accB) {
    int k = 0;
    for (; k + 3 < cnt; k += 4) {
        int i0 = sorted[s0 + k];
        int i1 = sorted[s0 + k + 1];
        int i2 = sorted[s0 + k + 2];
        int i3 = sorted[s0 + k + 3];
        float4 v0 = x4[i0 * 8 + q];
        float4 v1 = x4[i1 * 8 + q];
        float4 v2 = x4[i2 * 8 + q];
        float4 v3 = x4[i3 * 8 + q];
        f4add(accA, v0); f4add(accB, v1); f4add(accA, v2); f4add(accB, v3);
    }
    for (; k < cnt; ++k) f4add(accA, x4[sorted[s0 + k] * 8 + q]);
}

// One 512-thread block per 128-node bucket: in-LDS counting sort of the
// bucket's fixed-capacity segment by local dst, then atomic-free register
// accumulation. Integer LDS atomics only (hardware ds_add_u32).
__global__ void __launch_bounds__(512)
sort_aggregate_kernel(const float4* __restrict__ x4,
                      const int* __restrict__ gcur,
                      const int* __restrict__ packed,
                      float4* __restrict__ out4, int n_nodes) {
    __shared__ int shist[NPB];
    __shared__ int soff[NPB];
    __shared__ int scur[NPB];
    __shared__ int sorted[CAPB];

    int b = blockIdx.x;
    int t = threadIdx.x;
    int ecnt = min(gcur[b], CAPB);           // matches partition overflow guard
    const int* seg = packed + (size_t)b * CAPB;

    int node = t >> 3;        // 0..63 (batch 0: node, batch 1: node+64)
    int q    = t & 7;         // feature quad
    float4 a0A = {0,0,0,0}, a0B = {0,0,0,0};
    float4 a1A = {0,0,0,0}, a1B = {0,0,0,0};

    for (int i = t; i < NPB; i += 512) shist[i] = 0;
    __syncthreads();
    for (int i = t; i < ecnt; i += 512)
        atomicAdd(&shist[seg[i] & NPB_MASK], 1);
    __syncthreads();
    if (t < NPB) soff[t] = shist[t];
    __syncthreads();
    for (int off = 1; off < NPB; off <<= 1) {
        int v = (t < NPB && t >= off) ? soff[t - off] : 0;
        __syncthreads();
        if (t < NPB) soff[t] += v;
        __syncthreads();
    }
    if (t < NPB) {
        int e = soff[t] - shist[t];          // exclusive start
        soff[t] = e;
        scur[t] = e;
    }
    __syncthreads();
    for (int i = t; i < ecnt; i += 512) {
        int p = seg[i];
        int r = atomicAdd(&scur[p & NPB_MASK], 1);
        sorted[r] = p >> NPB_SHIFT;
    }
    __syncthreads();

    int deg0 = shist[node];
    accum_node(x4, sorted, soff[node], deg0, q, a0A, a0B);
    int deg1 = shist[node + 64];
    accum_node(x4, sorted, soff[node + 64], deg1, q, a1A, a1B);

    int n0 = b << NPB_SHIFT;
    int g0 = n0 + node;
    if (g0 < n_nodes) {
        float inv = 1.0f / (float)max(deg0, 1);
        float4 r;
        r.x = (a0A.x + a0B.x) * inv; r.y = (a0A.y + a0B.y) * inv;
        r.z = (a0A.z + a0B.z) * inv; r.w = (a0A.w + a0B.w) * inv;
        out4[(size_t)g0 * 8 + q] = r;
    }
    int g1 = n0 + 64 + node;
    if (g1 < n_nodes) {
        float inv = 1.0f / (float)max(deg1, 1);
        float4 r;
        r.x = (a1A.x + a1B.x) * inv; r.y = (a1A.y + a1B.y) * inv;
        r.z = (a1A.z + a1B.z) * inv; r.w = (a1A.w + a1B.w) * inv;
        out4[(size_t)g1 * 8 + q] = r;
    }
}

// ================= fallback: sorted (pull) path =================

__global__ void hist_kernel(const int* __restrict__ dst, int* __restrict__ counts,
                            int n_edges) {
    int t = blockIdx.x * blockDim.x + threadIdx.x;
    if (t < n_edges) atomicAdd(&counts[dst[t]], 1);
}

__global__ void scan_part1(const int* __restrict__ counts,
                           int* __restrict__ block_sums, int n) {
    __shared__ int sh[256];
    int base = blockIdx.x * TILE + threadIdx.x * 32;
    int s = 0;
#pragma unroll
    for (int i = 0; i < 32; ++i) {
        int idx = base + i;
        if (idx < n) s += counts[idx];
    }
    sh[threadIdx.x] = s;
    __syncthreads();
    for (int off = 128; off > 0; off >>= 1) {
        if (threadIdx.x < off) sh[threadIdx.x] += sh[threadIdx.x + off];
        __syncthreads();
    }
    if (threadIdx.x == 0) block_sums[blockIdx.x] = sh[0];
}

__global__ void scan_part2(int* __restrict__ block_sums, int nb) {
    if (blockIdx.x == 0 && threadIdx.x == 0) {
        int run = 0;
        for (int i = 0; i < nb; ++i) {
            int v = block_sums[i];
            block_sums[i] = run;
            run += v;
        }
    }
}

__global__ void scan_part3(const int* __restrict__ counts,
                           const int* __restrict__ block_sums,
                           int* __restrict__ offsets, int n) {
    __shared__ int sh[256];
    int tid = threadIdx.x;
    int base = blockIdx.x * TILE + tid * 32;
    int local[32];
    int s = 0;
#pragma unroll
    for (int i = 0; i < 32; ++i) {
        int idx = base + i;
        int v = (idx < n) ? counts[idx] : 0;
        local[i] = v;
        s += v;
    }
    sh[tid] = s;
    __syncthreads();
    for (int off = 1; off < 256; off <<= 1) {
        int v = (tid >= off) ? sh[tid - off] : 0;
        __syncthreads();
        sh[tid] += v;
        __syncthreads();
    }
    int run = block_sums[blockIdx.x] + ((tid == 0) ? 0 : sh[tid - 1]);
#pragma unroll
    for (int i = 0; i < 32; ++i) {
        int idx = base + i;
        if (idx < n) offsets[idx] = run;
        run += local[i];
    }
}

__global__ void scatter_sort_kernel(const int* __restrict__ src,
                                    const int* __restrict__ dst,
                                    int* __restrict__ cursors,
                                    int* __restrict__ sorted_src,
                                    int n_edges) {
    int t = blockIdx.x * blockDim.x + threadIdx.x;
    if (t < n_edges) {
        int pos = atomicAdd(&cursors[dst[t]], 1);
        sorted_src[pos] = src[t];
    }
}

__global__ void aggregate_kernel(const float* __restrict__ x,
                                 const int* __restrict__ seg_end,
                                 const int* __restrict__ sorted_src,
                                 float4* __restrict__ out,
                                 int n_nodes) {
    int t = blockIdx.x * blockDim.x + threadIdx.x;
    int n = t >> 3;
    if (n >= n_nodes) return;
    int q = t & 7;
    int end   = seg_end[n];
    int start = (n == 0) ? 0 : seg_end[n - 1];
    const float4* x4 = (const float4*)x;
    float4 acc0 = make_float4(0.f, 0.f, 0.f, 0.f);
    float4 acc1 = make_float4(0.f, 0.f, 0.f, 0.f);
    int k = start;
    for (; k + 1 < end; k += 2) {
        int s0 = sorted_src[k];
        int s1 = sorted_src[k + 1];
        f4add(acc0, x4[s0 * 8 + q]);
        f4add(acc1, x4[s1 * 8 + q]);
    }
    if (k < end) f4add(acc0, x4[sorted_src[k] * 8 + q]);
    float inv = 1.0f / (float)max(end - start, 1);
    float4 r;
    r.x = (acc0.x + acc1.x) * inv;
    r.y = (acc0.y + acc1.y) * inv;
    r.z = (acc0.z + acc1.z) * inv;
    r.w = (acc0.w + acc1.w) * inv;
    out[n * 8 + q] = r;
}

// ================= launch =================

extern "C" void kernel_launch(void* const* d_in, const int* in_sizes, int n_in,
                              void* d_out, int out_size, void* d_ws, size_t ws_size,
                              hipStream_t stream) {
    const float* x   = (const float*)d_in[0];
    const int*   src = (const int*)d_in[1];
    const int*   dst = (const int*)d_in[2];
    float* out = (float*)d_out;

    int n_nodes = in_sizes[0] / DIM;
    int n_edges = in_sizes[1];

    int nbuckets = (n_nodes + NPB - 1) >> NPB_SHIFT;
    int pblocks  = (n_edges + PCHUNK - 1) / PCHUNK;
    size_t need = ((size_t)nbuckets * (CAPB + 1)) * sizeof(int);
    bool fast_ok = (n_nodes < (1 << 24)) && (nbuckets <= MAXB) &&
                   ((size_t)n_edges * 2 <= (size_t)nbuckets * CAPB) &&
                   (ws_size >= need);

    if (fast_ok) {
        int* gcur   = (int*)d_ws;            // [nbuckets] cursors (-> counts)
        int* packed = gcur + nbuckets;       // [nbuckets * CAPB]

        zero_i32_kernel<<<(nbuckets + 255) / 256, 256, 0, stream>>>(gcur,
                                                                    nbuckets);
        if (pblocks > 0)
            partition_cap_kernel<<<pblocks, 512, 0, stream>>>(src, dst, gcur,
                                                              packed, n_edges,
                                                              nbuckets);
        sort_aggregate_kernel<<<nbuckets, 512, 0, stream>>>((const float4*)x,
                                                            gcur, packed,
                                                            (float4*)out,
                                                            n_nodes);
    } else {
        // fallback: dst-sorted pull path (verified generic pipeline)
        int nb = (n_nodes + TILE - 1) / TILE;
        int* counts     = (int*)d_ws;
        int* offsets    = counts + n_nodes;
        int* sorted_src = offsets + n_nodes;
        int* block_sums = sorted_src + n_edges;

        zero_i32_kernel<<<(n_nodes + 255) / 256, 256, 0, stream>>>(counts,
                                                                   n_nodes);
        int eb = (n_edges + 255) / 256;
        hist_kernel<<<eb, 256, 0, stream>>>(dst, counts, n_edges);
        scan_part1<<<nb, 256, 0, stream>>>(counts, block_sums, n_nodes);
        scan_part2<<<1, 64, 0, stream>>>(block_sums, nb);
        scan_part3<<<nb, 256, 0, stream>>>(counts, block_sums, offsets, n_nodes);
        scatter_sort_kernel<<<eb, 256, 0, stream>>>(src, dst, offsets,
                                                    sorted_src, n_edges);
        int athreads = n_nodes * 8;
        int ab = (athreads + 255) / 256;
        aggregate_kernel<<<ab, 256, 0, stream>>>(x, offsets, sorted_src,
                                                 (float4*)out, n_nodes);
    }
}

// Round 3
// 117.329 us; speedup vs baseline: 3.7593x; 1.0210x over previous
//
#include <hip/hip_runtime.h>

#define DIM 32
#define NPB 128            // nodes per bucket
#define NPB_SHIFT 7
#define NPB_MASK 127
#define MAXB 1024          // max buckets supported
#define PCHUNK 4096        // edges per partition block (512 thr x 8)
#define CAPB 4096          // per-bucket packed capacity (>= 2x mean, gated host-side)
#define SCALE 262144.0f    // 2^18 fixed-point scale for int LDS accumulation
#define INV_SCALE (1.0f / 262144.0f)
#define TILE 8192          // legacy scan tile (fallback path)

__global__ void zero_i32_kernel(int* __restrict__ p, int n) {
    int t = blockIdx.x * blockDim.x + threadIdx.x;
    if (t < n) p[t] = 0;
}

// ====== fast path: fixed-capacity bucket partition + int-LDS-atomic accum ====

// Partition edges into fixed-capacity bucket regions packed[b*CAPB ...].
// Per block: stash 8 edges/thread in registers, LDS count (atomic return =
// local rank), ONE global atomicAdd per touched bucket to reserve a contiguous
// slice, then scatter. packed = (src << NPB_SHIFT) | (dst & NPB_MASK).
// Order within a bucket is nondeterministic; accumulation is order-invariant
// (integer adds), so results stay deterministic.
__global__ void __launch_bounds__(512)
partition_cap_kernel(const int* __restrict__ src, const int* __restrict__ dst,
                     int* __restrict__ gcur, int* __restrict__ packed,
                     int n_edges, int nbuckets) {
    __shared__ int lcnt[MAXB];
    __shared__ int lbase[MAXB];
    int t = threadIdx.x;
    for (int j = t; j < nbuckets; j += 512) lcnt[j] = 0;
    __syncthreads();

    int c0 = blockIdx.x * PCHUNK;
    int c1 = min(c0 + PCHUNK, n_edges);

    int bb[8], pk[8], rr[8];   // static-indexed only (no scratch)
#pragma unroll
    for (int g = 0; g < 2; ++g) {
        int i = c0 + g * 2048 + t * 4;
        int4 d, s;
        if (i + 3 < c1) {
            d = *(const int4*)(dst + i);
            s = *(const int4*)(src + i);
        } else {
            d.x = (i + 0 < c1) ? dst[i + 0] : -1;
            d.y = (i + 1 < c1) ? dst[i + 1] : -1;
            d.z = (i + 2 < c1) ? dst[i + 2] : -1;
            d.w = (i + 3 < c1) ? dst[i + 3] : -1;
            s.x = (i + 0 < c1) ? src[i + 0] : 0;
            s.y = (i + 1 < c1) ? src[i + 1] : 0;
            s.z = (i + 2 < c1) ? src[i + 2] : 0;
            s.w = (i + 3 < c1) ? src[i + 3] : 0;
        }
        bb[g * 4 + 0] = (d.x >= 0) ? (d.x >> NPB_SHIFT) : -1;
        bb[g * 4 + 1] = (d.y >= 0) ? (d.y >> NPB_SHIFT) : -1;
        bb[g * 4 + 2] = (d.z >= 0) ? (d.z >> NPB_SHIFT) : -1;
        bb[g * 4 + 3] = (d.w >= 0) ? (d.w >> NPB_SHIFT) : -1;
        pk[g * 4 + 0] = (s.x << NPB_SHIFT) | (d.x & NPB_MASK);
        pk[g * 4 + 1] = (s.y << NPB_SHIFT) | (d.y & NPB_MASK);
        pk[g * 4 + 2] = (s.z << NPB_SHIFT) | (d.z & NPB_MASK);
        pk[g * 4 + 3] = (s.w << NPB_SHIFT) | (d.w & NPB_MASK);
    }
#pragma unroll
    for (int k = 0; k < 8; ++k)
        if (bb[k] >= 0) rr[k] = atomicAdd(&lcnt[bb[k]], 1);
    __syncthreads();
    for (int j = t; j < nbuckets; j += 512) {
        int c = lcnt[j];
        if (c > 0) lbase[j] = j * CAPB + atomicAdd(&gcur[j], c);
    }
    __syncthreads();
#pragma unroll
    for (int k = 0; k < 8; ++k)
        if (bb[k] >= 0) {
            int b = bb[k];
            int pos = lbase[b] + rr[k];
            if (pos < (b + 1) * CAPB) packed[pos] = pk[k];  // overflow guard
        }
}

// Swizzled LDS accumulator index for node ld, quad q, component c:
//   addr = ld*32 + ((q + 8c + ld) & 31)
// Per ds_add instruction (fixed c): each edge-group's 8 q-lanes occupy 8
// consecutive banks rotated by the group's random ld -> ~2-way avg (free).
__device__ __forceinline__ int aidx(int ld, int q, int c) {
    return (ld << 5) + ((q + (c << 3) + ld) & 31);
}

__device__ __forceinline__ void edge_accum(int* acc, int* scnt,
                                           const float4* __restrict__ x4,
                                           int p, int q) {
    int ld   = p & NPB_MASK;
    int srow = p >> NPB_SHIFT;
    float4 v = x4[srow * 8 + q];
    int ix = __float2int_rn(v.x * SCALE);
    int iy = __float2int_rn(v.y * SCALE);
    int iz = __float2int_rn(v.z * SCALE);
    int iw = __float2int_rn(v.w * SCALE);
    atomicAdd(&acc[aidx(ld, q, 0)], ix);
    atomicAdd(&acc[aidx(ld, q, 1)], iy);
    atomicAdd(&acc[aidx(ld, q, 2)], iz);
    atomicAdd(&acc[aidx(ld, q, 3)], iw);
    if (q == 0) atomicAdd(&scnt[ld], 1);
}

// One 512-thread block per 128-node bucket. Divergence-free edge-parallel
// loop: 8 lanes per edge, each lane loads one float4 of x[src], converts to
// fixed-point, and does 4 native ds_add_u32 into the swizzled accumulator.
// Single pass over the segment; no sort, no scan.
__global__ void __launch_bounds__(512)
accum_int_kernel(const float4* __restrict__ x4,
                 const int* __restrict__ gcur,
                 const int* __restrict__ packed,
                 float4* __restrict__ out4, int n_nodes) {
    __shared__ int acc[NPB * DIM];   // 16 KB
    __shared__ int scnt[NPB];
    int b = blockIdx.x;
    int t = threadIdx.x;
    for (int j = t; j < NPB * DIM; j += 512) acc[j] = 0;
    if (t < NPB) scnt[t] = 0;
    __syncthreads();

    int ecnt = min(gcur[b], CAPB);       // matches partition overflow guard
    const int* seg = packed + (size_t)b * CAPB;

    int g = t >> 3;                      // edge group 0..63
    int q = t & 7;                       // feature quad
    int e = g;
    for (; e + 192 < ecnt; e += 256) {   // 4 gathers in flight
        int p0 = seg[e];
        int p1 = seg[e + 64];
        int p2 = seg[e + 128];
        int p3 = seg[e + 192];
        edge_accum(acc, scnt, x4, p0, q);
        edge_accum(acc, scnt, x4, p1, q);
        edge_accum(acc, scnt, x4, p2, q);
        edge_accum(acc, scnt, x4, p3, q);
    }
    for (; e < ecnt; e += 64)
        edge_accum(acc, scnt, x4, seg[e], q);
    __syncthreads();

    int n0 = b << NPB_SHIFT;
    for (int j = t; j < NPB * 8; j += 512) {
        int node = j >> 3;
        int qq   = j & 7;
        int gn   = n0 + node;
        if (gn < n_nodes) {
            float inv = 1.0f / ((float)max(scnt[node], 1)) * INV_SCALE;
            float4 r;
            r.x = (float)acc[aidx(node, qq, 0)] * inv;
            r.y = (float)acc[aidx(node, qq, 1)] * inv;
            r.z = (float)acc[aidx(node, qq, 2)] * inv;
            r.w = (float)acc[aidx(node, qq, 3)] * inv;
            out4[(size_t)gn * 8 + qq] = r;
        }
    }
}

// ================= fallback: sorted (pull) path =================

__global__ void hist_kernel(const int* __restrict__ dst, int* __restrict__ counts,
                            int n_edges) {
    int t = blockIdx.x * blockDim.x + threadIdx.x;
    if (t < n_edges) atomicAdd(&counts[dst[t]], 1);
}

__global__ void scan_part1(const int* __restrict__ counts,
                           int* __restrict__ block_sums, int n) {
    __shared__ int sh[256];
    int base = blockIdx.x * TILE + threadIdx.x * 32;
    int s = 0;
#pragma unroll
    for (int i = 0; i < 32; ++i) {
        int idx = base + i;
        if (idx < n) s += counts[idx];
    }
    sh[threadIdx.x] = s;
    __syncthreads();
    for (int off = 128; off > 0; off >>= 1) {
        if (threadIdx.x < off) sh[threadIdx.x] += sh[threadIdx.x + off];
        __syncthreads();
    }
    if (threadIdx.x == 0) block_sums[blockIdx.x] = sh[0];
}

__global__ void scan_part2(int* __restrict__ block_sums, int nb) {
    if (blockIdx.x == 0 && threadIdx.x == 0) {
        int run = 0;
        for (int i = 0; i < nb; ++i) {
            int v = block_sums[i];
            block_sums[i] = run;
            run += v;
        }
    }
}

__global__ void scan_part3(const int* __restrict__ counts,
                           const int* __restrict__ block_sums,
                           int* __restrict__ offsets, int n) {
    __shared__ int sh[256];
    int tid = threadIdx.x;
    int base = blockIdx.x * TILE + tid * 32;
    int local[32];
    int s = 0;
#pragma unroll
    for (int i = 0; i < 32; ++i) {
        int idx = base + i;
        int v = (idx < n) ? counts[idx] : 0;
        local[i] = v;
        s += v;
    }
    sh[tid] = s;
    __syncthreads();
    for (int off = 1; off < 256; off <<= 1) {
        int v = (tid >= off) ? sh[tid - off] : 0;
        __syncthreads();
        sh[tid] += v;
        __syncthreads();
    }
    int run = block_sums[blockIdx.x] + ((tid == 0) ? 0 : sh[tid - 1]);
#pragma unroll
    for (int i = 0; i < 32; ++i) {
        int idx = base + i;
        if (idx < n) offsets[idx] = run;
        run += local[i];
    }
}

__global__ void scatter_sort_kernel(const int* __restrict__ src,
                                    const int* __restrict__ dst,
                                    int* __restrict__ cursors,
                                    int* __restrict__ sorted_src,
                                    int n_edges) {
    int t = blockIdx.x * blockDim.x + threadIdx.x;
    if (t < n_edges) {
        int pos = atomicAdd(&cursors[dst[t]], 1);
        sorted_src[pos] = src[t];
    }
}

__device__ inline void f4add(float4& a, float4 v) {
    a.x += v.x; a.y += v.y; a.z += v.z; a.w += v.w;
}

__global__ void aggregate_kernel(const float* __restrict__ x,
                                 const int* __restrict__ seg_end,
                                 const int* __restrict__ sorted_src,
                                 float4* __restrict__ out,
                                 int n_nodes) {
    int t = blockIdx.x * blockDim.x + threadIdx.x;
    int n = t >> 3;
    if (n >= n_nodes) return;
    int q = t & 7;
    int end   = seg_end[n];
    int start = (n == 0) ? 0 : seg_end[n - 1];
    const float4* x4 = (const float4*)x;
    float4 acc0 = make_float4(0.f, 0.f, 0.f, 0.f);
    float4 acc1 = make_float4(0.f, 0.f, 0.f, 0.f);
    int k = start;
    for (; k + 1 < end; k += 2) {
        int s0 = sorted_src[k];
        int s1 = sorted_src[k + 1];
        f4add(acc0, x4[s0 * 8 + q]);
        f4add(acc1, x4[s1 * 8 + q]);
    }
    if (k < end) f4add(acc0, x4[sorted_src[k] * 8 + q]);
    float inv = 1.0f / (float)max(end - start, 1);
    float4 r;
    r.x = (acc0.x + acc1.x) * inv;
    r.y = (acc0.y + acc1.y) * inv;
    r.z = (acc0.z + acc1.z) * inv;
    r.w = (acc0.w + acc1.w) * inv;
    out[n * 8 + q] = r;
}

// ================= launch =================

extern "C" void kernel_launch(void* const* d_in, const int* in_sizes, int n_in,
                              void* d_out, int out_size, void* d_ws, size_t ws_size,
                              hipStream_t stream) {
    const float* x   = (const float*)d_in[0];
    const int*   src = (const int*)d_in[1];
    const int*   dst = (const int*)d_in[2];
    float* out = (float*)d_out;

    int n_nodes = in_sizes[0] / DIM;
    int n_edges = in_sizes[1];

    int nbuckets = (n_nodes + NPB - 1) >> NPB_SHIFT;
    int pblocks  = (n_edges + PCHUNK - 1) / PCHUNK;
    size_t need = ((size_t)nbuckets * (CAPB + 1)) * sizeof(int);
    bool fast_ok = (n_nodes < (1 << 24)) && (nbuckets <= MAXB) &&
                   ((size_t)n_edges * 2 <= (size_t)nbuckets * CAPB) &&
                   (ws_size >= need);

    if (fast_ok) {
        int* gcur   = (int*)d_ws;            // [nbuckets] cursors (-> counts)
        int* packed = gcur + nbuckets;       // [nbuckets * CAPB]

        zero_i32_kernel<<<(nbuckets + 255) / 256, 256, 0, stream>>>(gcur,
                                                                    nbuckets);
        if (pblocks > 0)
            partition_cap_kernel<<<pblocks, 512, 0, stream>>>(src, dst, gcur,
                                                              packed, n_edges,
                                                              nbuckets);
        accum_int_kernel<<<nbuckets, 512, 0, stream>>>((const float4*)x,
                                                       gcur, packed,
                                                       (float4*)out, n_nodes);
    } else {
        // fallback: dst-sorted pull path (verified generic pipeline)
        int nb = (n_nodes + TILE - 1) / TILE;
        int* counts     = (int*)d_ws;
        int* offsets    = counts + n_nodes;
        int* sorted_src = offsets + n_nodes;
        int* block_sums = sorted_src + n_edges;

        zero_i32_kernel<<<(n_nodes + 255) / 256, 256, 0, stream>>>(counts,
                                                                   n_nodes);
        int eb = (n_edges + 255) / 256;
        hist_kernel<<<eb, 256, 0, stream>>>(dst, counts, n_edges);
        scan_part1<<<nb, 256, 0, stream>>>(counts, block_sums, n_nodes);
        scan_part2<<<1, 64, 0, stream>>>(block_sums, nb);
        scan_part3<<<nb, 256, 0, stream>>>(counts, block_sums, offsets, n_nodes);
        scatter_sort_kernel<<<eb, 256, 0, stream>>>(src, dst, offsets,
                                                    sorted_src, n_edges);
        int athreads = n_nodes * 8;
        int ab = (athreads + 255) / 256;
        aggregate_kernel<<<ab, 256, 0, stream>>>(x, offsets, sorted_src,
                                                 (float4*)out, n_nodes);
    }
}